// Round 1
// baseline (493.355 us; speedup 1.0000x reference)
//
#include <hip/hip_runtime.h>
#include <math.h>

// Problem constants (reference: N, L, LQ, D, AF, K = 4096, 512, 32, 30, 10, 4)
#define NS 4096
#define LL 512
#define LQS 32
#define DD 30
#define AFN 10
#define KW 4

// Workspace layout (floats)
enum {
  QRAW = 0,     // [30] mean of question_embeds over LQ
  Q1G  = 30,    // [30] gpool of conv1(q)
  Q2G  = 60,    // [30] gpool of conv2(windowpool(conv1(q)))
  NRM  = 90,    // [3]  norms of the three q vectors
  WS1  = 96,    // [900] sum_k conv1_w[o][i][k]
  WS2  = 996,   // [900] sum_k conv2_w[o][i][k]
  OA0  = 1896,  // [900] 3*w3 + 2*w2 + w1   (left-edge coeff for row 0)
  OA1  = 2796,  // [900] 2*w3 + w2          (row 1)
  OA2  = 3696,  // [900] w3                 (row 2)
  OB0  = 4596,  // [900] w0                 (row L-3)
  OB1  = 5496,  // [900] w1 + 2*w0          (row L-2)
  OB2  = 6396,  // [900] w2 + 2*w1 + 3*w0   (row L-1)
  WS_TOTAL = 7296
};

// ---------------------------------------------------------------------------
// Kernel 1: question-side pipeline (exact, tiny) + weight transforms + zero
// the cost accumulator. One block, 256 threads.
// ---------------------------------------------------------------------------
__global__ __launch_bounds__(256) void prep_kernel(
    const float* __restrict__ qe,   // [LQ, D]
    const float* __restrict__ w1,   // [D, D, K]
    const float* __restrict__ b1,   // [D]
    const float* __restrict__ w2,   // [D, D, K]
    const float* __restrict__ b2,   // [D]
    float* __restrict__ ws,
    float* __restrict__ out)
{
    __shared__ float qT[DD][LQS];      // q[channel][t]
    __shared__ float q1c[DD][LQS + 3];
    __shared__ float q1w[DD][LQS];
    __shared__ float q2c[DD][LQS + 3];
    __shared__ float qpool[3][DD];
    const int tid = threadIdx.x;

    // load question embeds transposed: qe[lq, d] -> qT[d][lq]
    for (int f = tid; f < LQS * DD; f += 256) {
        qT[f % DD][f / DD] = qe[f];
    }
    __syncthreads();

    // conv1: q1c[o][t] = sum_{i,k} qT[i][t+k-3] * w1[o][i][k] + b1[o]
    for (int idx = tid; idx < DD * (LQS + 3); idx += 256) {
        int o = idx / (LQS + 3), t = idx % (LQS + 3);
        float acc = b1[o];
        for (int i = 0; i < DD; i++) {
            const float* w = w1 + (o * DD + i) * KW;
            #pragma unroll
            for (int k = 0; k < KW; k++) {
                int j = t + k - 3;
                if (j >= 0 && j < LQS) acc += qT[i][j] * w[k];
            }
        }
        q1c[o][t] = acc;
    }
    __syncthreads();

    // window pool (kernel 4, stride 1, VALID)
    for (int idx = tid; idx < DD * LQS; idx += 256) {
        int o = idx / LQS, t = idx % LQS;
        q1w[o][t] = 0.25f * (q1c[o][t] + q1c[o][t + 1] + q1c[o][t + 2] + q1c[o][t + 3]);
    }
    __syncthreads();

    // conv2
    for (int idx = tid; idx < DD * (LQS + 3); idx += 256) {
        int o = idx / (LQS + 3), t = idx % (LQS + 3);
        float acc = b2[o];
        for (int i = 0; i < DD; i++) {
            const float* w = w2 + (o * DD + i) * KW;
            #pragma unroll
            for (int k = 0; k < KW; k++) {
                int j = t + k - 3;
                if (j >= 0 && j < LQS) acc += q1w[i][j] * w[k];
            }
        }
        q2c[o][t] = acc;
    }
    __syncthreads();

    // global pools
    if (tid < DD) {
        float a = 0.f;
        for (int t = 0; t < LQS; t++) a += qT[tid][t];
        qpool[0][tid] = a * (1.0f / LQS);
        float g1 = 0.f;
        for (int t = 0; t < LQS + 3; t++) g1 += q1c[tid][t];
        qpool[1][tid] = g1 * (1.0f / (LQS + 3));
        float g2 = 0.f;
        for (int t = 0; t < LQS + 3; t++) g2 += q2c[tid][t];
        qpool[2][tid] = g2 * (1.0f / (LQS + 3));
        ws[QRAW + tid] = qpool[0][tid];
        ws[Q1G + tid]  = qpool[1][tid];
        ws[Q2G + tid]  = qpool[2][tid];
    }
    __syncthreads();
    if (tid < 3) {
        float s = 0.f;
        for (int i = 0; i < DD; i++) { float v = qpool[tid][i]; s += v * v; }
        ws[NRM + tid] = sqrtf(s);
    }
    if (tid == 0) out[0] = 0.0f;  // cost accumulator (d_out is poisoned 0xAA)

    // weight transforms for the analytic sentence-side pipeline
    for (int idx = tid; idx < DD * DD; idx += 256) {
        const float* w = w1 + idx * KW;
        float a = w[0], b = w[1], c = w[2], d = w[3];
        ws[WS1 + idx] = a + b + c + d;
        ws[OA0 + idx] = 3.f * d + 2.f * c + b;
        ws[OA1 + idx] = 2.f * d + c;
        ws[OA2 + idx] = d;
        ws[OB0 + idx] = a;
        ws[OB1 + idx] = b + 2.f * a;
        ws[OB2 + idx] = c + 2.f * b + 3.f * a;
        const float* v = w2 + idx * KW;
        ws[WS2 + idx] = v[0] + v[1] + v[2] + v[3];
    }
}

// ---------------------------------------------------------------------------
// Kernel 2: one block per sentence. Stream 61440 B with float4, reduce to
// channel sums S[30] + 6 boundary rows, then tiny analytic math -> sims ->
// MLP -> log-softmax -> emit + cost.
// ---------------------------------------------------------------------------
__global__ __launch_bounds__(256) void sent_kernel(
    const float* __restrict__ se,    // [N, L, D]
    const float* __restrict__ gaf,   // [N, AF]
    const int*   __restrict__ labels,// [N]
    const float* __restrict__ b1,    // [D]
    const float* __restrict__ b2,    // [D]
    const float* __restrict__ linw,  // [2, 13]
    const float* __restrict__ linb,  // [2]
    const float* __restrict__ ws,
    float* __restrict__ out)         // [1 + N]
{
    const int n = blockIdx.x;
    const int tid = threadIdx.x;
    const float* base = se + (size_t)n * (LL * DD);

    __shared__ float partial[960];   // 240 threads * 4 lanes, flat index = channel pattern
    __shared__ float bnd[6][DD];     // rows 0,1,2,509,510,511
    __shared__ float S[DD], Tv[DD], s1g[DD], s2g[DD];
    __shared__ float red[6][32];

    // Phase A: channel sums. 240 threads * float4 = 960 floats = 32 rows/pass,
    // stride 960 ≡ 0 (mod 30) so flat-index -> channel mapping is pass-invariant.
    if (tid < 240) {
        const float4* p = (const float4*)base + tid;
        float4 acc = make_float4(0.f, 0.f, 0.f, 0.f);
        #pragma unroll
        for (int it = 0; it < 16; it++) {
            float4 v = p[it * 240];
            acc.x += v.x; acc.y += v.y; acc.z += v.z; acc.w += v.w;
        }
        partial[4 * tid + 0] = acc.x;
        partial[4 * tid + 1] = acc.y;
        partial[4 * tid + 2] = acc.z;
        partial[4 * tid + 3] = acc.w;
    }
    // boundary rows (also counted in S; needed separately for edge correction)
    if (tid < 180) {
        int r = tid / DD, c = tid % DD;
        int j = (r < 3) ? r : (LL - 6 + r);  // 0,1,2,509,510,511
        bnd[r][c] = base[j * DD + c];
    }
    __syncthreads();

    // flat partial index v corresponds to channel v % 30 (since 960 % 30 == 0)
    if (tid < DD) {
        float a = 0.f;
        #pragma unroll
        for (int m = 0; m < 32; m++) a += partial[tid + DD * m];
        S[tid] = a;
    }
    __syncthreads();

    // Phase B: analytic s1g / T
    if (tid < DD) {
        const int i = tid;
        const float* ws1 = ws + WS1 + i * DD;
        const float* a0  = ws + OA0 + i * DD;
        const float* a1  = ws + OA1 + i * DD;
        const float* a2  = ws + OA2 + i * DD;
        const float* c0  = ws + OB0 + i * DD;
        const float* c1  = ws + OB1 + i * DD;
        const float* c2  = ws + OB2 + i * DD;
        float dotS = 0.f, edge = 0.f;
        for (int ii = 0; ii < DD; ii++) {
            dotS += S[ii] * ws1[ii];
            edge += bnd[0][ii] * a0[ii] + bnd[1][ii] * a1[ii] + bnd[2][ii] * a2[ii]
                  + bnd[3][ii] * c0[ii] + bnd[4][ii] * c1[ii] + bnd[5][ii] * c2[ii];
        }
        const float bias = b1[i];
        s1g[i] = dotS * (1.0f / (LL + 3)) + bias;
        Tv[i]  = dotS + (float)LL * bias - 0.25f * edge;
    }
    __syncthreads();

    if (tid < DD) {
        const float* ws2 = ws + WS2 + tid * DD;
        float a = 0.f;
        for (int ii = 0; ii < DD; ii++) a += Tv[ii] * ws2[ii];
        s2g[tid] = a * (1.0f / (LL + 3)) + b2[tid];
    }
    __syncthreads();

    // six dot products of length 30 (cos is scale-invariant in s_raw -> use S)
    if (tid < DD) {
        float qv = (n == 0) ? ws[QRAW + tid] : ws[Q2G + tid];
        red[0][tid] = qv * S[tid];
        red[1][tid] = S[tid] * S[tid];
        red[2][tid] = ws[Q1G + tid] * s1g[tid];
        red[3][tid] = s1g[tid] * s1g[tid];
        red[4][tid] = ws[Q2G + tid] * s2g[tid];
        red[5][tid] = s2g[tid] * s2g[tid];
    }
    __syncthreads();
    if (tid < 6) {
        float a = 0.f;
        for (int i = 0; i < DD; i++) a += red[tid][i];
        red[tid][31] = a;
    }
    __syncthreads();

    if (tid == 0) {
        float nq = (n == 0) ? ws[NRM + 0] : ws[NRM + 2];
        float sim1 = red[0][31] / (nq * sqrtf(red[1][31]));
        float sim2 = red[2][31] / (ws[NRM + 1] * sqrtf(red[3][31]));
        float sim3 = red[4][31] / (ws[NRM + 2] * sqrtf(red[5][31]));

        float in[3 + AFN];
        in[0] = sim1; in[1] = sim2; in[2] = sim3;
        const float* g = gaf + (size_t)n * AFN;
        #pragma unroll
        for (int j = 0; j < AFN; j++) in[3 + j] = g[j];

        float l0 = linb[0], l1 = linb[1];
        #pragma unroll
        for (int j = 0; j < 3 + AFN; j++) {
            l0 += in[j] * linw[j];
            l1 += in[j] * linw[(3 + AFN) + j];
        }
        // log_softmax
        float m = fmaxf(l0, l1);
        float lse = m + logf(expf(l0 - m) + expf(l1 - m));
        float lp0 = l0 - lse, lp1 = l1 - lse;
        // emit = softmax(log_softmax(logits))[1]
        float mm = fmaxf(lp0, lp1);
        float e0 = expf(lp0 - mm), e1 = expf(lp1 - mm);
        out[1 + n] = e1 / (e0 + e1);
        // cost contribution
        int lab = labels[n];
        float lp = (lab == 0) ? lp0 : lp1;
        atomicAdd(&out[0], -lp * (1.0f / NS));
    }
}

// ---------------------------------------------------------------------------
extern "C" void kernel_launch(void* const* d_in, const int* in_sizes, int n_in,
                              void* d_out, int out_size, void* d_ws, size_t ws_size,
                              hipStream_t stream)
{
    (void)in_sizes; (void)n_in; (void)out_size; (void)ws_size;
    const float* se  = (const float*)d_in[0];
    const float* qe  = (const float*)d_in[1];
    const float* gaf = (const float*)d_in[2];
    const int*   lab = (const int*)d_in[3];
    const float* w1  = (const float*)d_in[4];
    const float* b1  = (const float*)d_in[5];
    const float* w2  = (const float*)d_in[6];
    const float* b2  = (const float*)d_in[7];
    const float* lw  = (const float*)d_in[8];
    const float* lb  = (const float*)d_in[9];
    float* out = (float*)d_out;
    float* ws  = (float*)d_ws;   // needs WS_TOTAL*4 = 29184 bytes

    hipLaunchKernelGGL(prep_kernel, dim3(1), dim3(256), 0, stream,
                       qe, w1, b1, w2, b2, ws, out);
    hipLaunchKernelGGL(sent_kernel, dim3(NS), dim3(256), 0, stream,
                       se, gaf, lab, b1, b2, lw, lb, ws, out);
}

// Round 2
// 489.603 us; speedup vs baseline: 1.0077x; 1.0077x over previous
//
#include <hip/hip_runtime.h>
#include <math.h>

// Problem constants (reference: N, L, LQ, D, AF, K = 4096, 512, 32, 30, 10, 4)
#define NS 4096
#define LL 512
#define LQS 32
#define DD 30
#define AFN 10
#define KW 4

// Workspace layout (floats)
enum {
  QRAW = 0,     // [30] mean of question_embeds over LQ
  Q1G  = 30,    // [30] gpool of conv1(q)
  Q2G  = 60,    // [30] gpool of conv2(windowpool(conv1(q)))
  NRM  = 90,    // [3]  norms of the three q vectors
  WS1  = 96,    // [900] sum_k conv1_w[o][i][k]
  WS2  = 996,   // [900] sum_k conv2_w[o][i][k]
  OA0  = 1896,  // [900] 3*w3 + 2*w2 + w1   (left-edge coeff for row 0)
  OA1  = 2796,  // [900] 2*w3 + w2          (row 1)
  OA2  = 3696,  // [900] w3                 (row 2)
  OB0  = 4596,  // [900] w0                 (row L-3)
  OB1  = 5496,  // [900] w1 + 2*w0          (row L-2)
  OB2  = 6396,  // [900] w2 + 2*w1 + 3*w0   (row L-1)
  SARR = 7296,  // [NS*DD] per-sentence channel sums
  WS_TOTAL = SARR + NS * DD
};

// ---------------------------------------------------------------------------
// Kernel 1: question-side pipeline (exact, tiny) + weight transforms + zero
// the cost accumulator. One block, 256 threads.
// ---------------------------------------------------------------------------
__global__ __launch_bounds__(256) void prep_kernel(
    const float* __restrict__ qe,   // [LQ, D]
    const float* __restrict__ w1,   // [D, D, K]
    const float* __restrict__ b1,   // [D]
    const float* __restrict__ w2,   // [D, D, K]
    const float* __restrict__ b2,   // [D]
    float* __restrict__ ws,
    float* __restrict__ out)
{
    __shared__ float qT[DD][LQS];      // q[channel][t]
    __shared__ float q1c[DD][LQS + 3];
    __shared__ float q1w[DD][LQS];
    __shared__ float q2c[DD][LQS + 3];
    __shared__ float qpool[3][DD];
    const int tid = threadIdx.x;

    for (int f = tid; f < LQS * DD; f += 256) {
        qT[f % DD][f / DD] = qe[f];
    }
    __syncthreads();

    // conv1
    for (int idx = tid; idx < DD * (LQS + 3); idx += 256) {
        int o = idx / (LQS + 3), t = idx % (LQS + 3);
        float acc = b1[o];
        for (int i = 0; i < DD; i++) {
            const float* w = w1 + (o * DD + i) * KW;
            #pragma unroll
            for (int k = 0; k < KW; k++) {
                int j = t + k - 3;
                if (j >= 0 && j < LQS) acc += qT[i][j] * w[k];
            }
        }
        q1c[o][t] = acc;
    }
    __syncthreads();

    // window pool
    for (int idx = tid; idx < DD * LQS; idx += 256) {
        int o = idx / LQS, t = idx % LQS;
        q1w[o][t] = 0.25f * (q1c[o][t] + q1c[o][t + 1] + q1c[o][t + 2] + q1c[o][t + 3]);
    }
    __syncthreads();

    // conv2
    for (int idx = tid; idx < DD * (LQS + 3); idx += 256) {
        int o = idx / (LQS + 3), t = idx % (LQS + 3);
        float acc = b2[o];
        for (int i = 0; i < DD; i++) {
            const float* w = w2 + (o * DD + i) * KW;
            #pragma unroll
            for (int k = 0; k < KW; k++) {
                int j = t + k - 3;
                if (j >= 0 && j < LQS) acc += q1w[i][j] * w[k];
            }
        }
        q2c[o][t] = acc;
    }
    __syncthreads();

    if (tid < DD) {
        float a = 0.f;
        for (int t = 0; t < LQS; t++) a += qT[tid][t];
        qpool[0][tid] = a * (1.0f / LQS);
        float g1 = 0.f;
        for (int t = 0; t < LQS + 3; t++) g1 += q1c[tid][t];
        qpool[1][tid] = g1 * (1.0f / (LQS + 3));
        float g2 = 0.f;
        for (int t = 0; t < LQS + 3; t++) g2 += q2c[tid][t];
        qpool[2][tid] = g2 * (1.0f / (LQS + 3));
        ws[QRAW + tid] = qpool[0][tid];
        ws[Q1G + tid]  = qpool[1][tid];
        ws[Q2G + tid]  = qpool[2][tid];
    }
    __syncthreads();
    if (tid < 3) {
        float s = 0.f;
        for (int i = 0; i < DD; i++) { float v = qpool[tid][i]; s += v * v; }
        ws[NRM + tid] = sqrtf(s);
    }
    if (tid == 0) out[0] = 0.0f;  // cost accumulator

    // weight transforms
    for (int idx = tid; idx < DD * DD; idx += 256) {
        const float* w = w1 + idx * KW;
        float a = w[0], b = w[1], c = w[2], d = w[3];
        ws[WS1 + idx] = a + b + c + d;
        ws[OA0 + idx] = 3.f * d + 2.f * c + b;
        ws[OA1 + idx] = 2.f * d + c;
        ws[OA2 + idx] = d;
        ws[OB0 + idx] = a;
        ws[OB1 + idx] = b + 2.f * a;
        ws[OB2 + idx] = c + 2.f * b + 3.f * a;
        const float* v = w2 + idx * KW;
        ws[WS2 + idx] = v[0] + v[1] + v[2] + v[3];
    }
}

// ---------------------------------------------------------------------------
// Kernel 2: PURE streaming. One block per sentence, 240 threads x 16 float4,
// LDS reduce to channel sums S[30] -> ws. No tail, one barrier.
// ---------------------------------------------------------------------------
__global__ __launch_bounds__(256) void stream_kernel(
    const float* __restrict__ se,    // [N, L, D]
    float* __restrict__ ws)
{
    const int n = blockIdx.x;
    const int tid = threadIdx.x;
    const float* base = se + (size_t)n * (LL * DD);

    __shared__ float partial[960];

    if (tid < 240) {
        const float4* p = (const float4*)base + tid;
        float sx = 0.f, sy = 0.f, sz = 0.f, sw = 0.f;
        #pragma unroll
        for (int it = 0; it < 16; it++) {
            float4 v = p[it * 240];
            sx += v.x; sy += v.y; sz += v.z; sw += v.w;
        }
        partial[4 * tid + 0] = sx;
        partial[4 * tid + 1] = sy;
        partial[4 * tid + 2] = sz;
        partial[4 * tid + 3] = sw;
    }
    __syncthreads();

    // flat index j aggregates channel j % 30 (960 % 30 == 0, 3840 % 30 == 0)
    if (tid < DD) {
        float a = 0.f;
        #pragma unroll
        for (int m = 0; m < 32; m++) a += partial[tid + DD * m];
        ws[SARR + n * DD + tid] = a;
    }
}

// ---------------------------------------------------------------------------
// Kernel 3: one sentence per WAVE (lanes 0..29 active), all cross-channel
// math via __shfl broadcasts. 1024 blocks x 256 threads = 4096 waves.
// Coefficient tables read from ws (L2-hot, 29 KB). Cost combined per block.
// ---------------------------------------------------------------------------
__global__ __launch_bounds__(256) void post_kernel(
    const float* __restrict__ se,    // [N, L, D]
    const float* __restrict__ gaf,   // [N, AF]
    const int*   __restrict__ labels,// [N]
    const float* __restrict__ b1,    // [D]
    const float* __restrict__ b2,    // [D]
    const float* __restrict__ linw,  // [2, 13]
    const float* __restrict__ linb,  // [2]
    const float* __restrict__ ws,
    float* __restrict__ out)         // [1 + N]
{
    const int tid  = threadIdx.x;
    const int wid  = tid >> 6;
    const int lane = tid & 63;
    const int n    = blockIdx.x * 4 + wid;

    __shared__ float costp[4];

    const bool act = (lane < DD);
    const int  ic  = act ? lane : 0;

    // per-lane channel data
    float S_i = 0.f, e0r = 0.f, e1r = 0.f, e2r = 0.f, e3r = 0.f, e4r = 0.f, e5r = 0.f;
    float bb1, bb2;
    {
        const float* base = se + (size_t)n * (LL * DD);
        S_i = ws[SARR + n * DD + ic];
        e0r = base[0 * DD + ic];
        e1r = base[1 * DD + ic];
        e2r = base[2 * DD + ic];
        e3r = base[509 * DD + ic];
        e4r = base[510 * DD + ic];
        e5r = base[511 * DD + ic];
        bb1 = b1[ic];
        bb2 = b2[ic];
    }

    // dotS[i] = sum_ii S[ii]*ws1[i][ii]; edge[i] analogous with 6 boundary tables
    float dotS = 0.f, edge = 0.f;
    const float* ws1 = ws + WS1 + ic * DD;
    const float* a0  = ws + OA0 + ic * DD;
    const float* a1  = ws + OA1 + ic * DD;
    const float* a2  = ws + OA2 + ic * DD;
    const float* c0  = ws + OB0 + ic * DD;
    const float* c1  = ws + OB1 + ic * DD;
    const float* c2  = ws + OB2 + ic * DD;
    #pragma unroll 6
    for (int ii = 0; ii < DD; ii++) {
        float s  = __shfl(S_i, ii, 64);
        float b0 = __shfl(e0r, ii, 64);
        float b1v = __shfl(e1r, ii, 64);
        float b2v = __shfl(e2r, ii, 64);
        float b3v = __shfl(e3r, ii, 64);
        float b4v = __shfl(e4r, ii, 64);
        float b5v = __shfl(e5r, ii, 64);
        dotS += s * ws1[ii];
        edge += b0 * a0[ii] + b1v * a1[ii] + b2v * a2[ii]
              + b3v * c0[ii] + b4v * c1[ii] + b5v * c2[ii];
    }
    float s1g = dotS * (1.0f / (LL + 3)) + bb1;
    float Tv  = dotS + (float)LL * bb1 - 0.25f * edge;

    float dot2 = 0.f;
    const float* ws2 = ws + WS2 + ic * DD;
    #pragma unroll 6
    for (int ii = 0; ii < DD; ii++) {
        float tv = __shfl(Tv, ii, 64);
        dot2 += tv * ws2[ii];
    }
    float s2g = dot2 * (1.0f / (LL + 3)) + bb2;

    // six dot products of length 30
    float qv = (n == 0) ? ws[QRAW + ic] : ws[Q2G + ic];
    float q1 = ws[Q1G + ic];
    float q2 = ws[Q2G + ic];
    float p0 = act ? qv * S_i : 0.f;
    float p1 = act ? S_i * S_i : 0.f;
    float p2 = act ? q1 * s1g : 0.f;
    float p3 = act ? s1g * s1g : 0.f;
    float p4 = act ? q2 * s2g : 0.f;
    float p5 = act ? s2g * s2g : 0.f;
    #pragma unroll
    for (int off = 32; off >= 1; off >>= 1) {
        p0 += __shfl_xor(p0, off, 64);
        p1 += __shfl_xor(p1, off, 64);
        p2 += __shfl_xor(p2, off, 64);
        p3 += __shfl_xor(p3, off, 64);
        p4 += __shfl_xor(p4, off, 64);
        p5 += __shfl_xor(p5, off, 64);
    }

    if (lane == 0) {
        float nq = (n == 0) ? ws[NRM + 0] : ws[NRM + 2];
        float sim1 = p0 / (nq * sqrtf(p1));
        float sim2 = p2 / (ws[NRM + 1] * sqrtf(p3));
        float sim3 = p4 / (ws[NRM + 2] * sqrtf(p5));

        float in[3 + AFN];
        in[0] = sim1; in[1] = sim2; in[2] = sim3;
        const float* g = gaf + (size_t)n * AFN;
        #pragma unroll
        for (int j = 0; j < AFN; j++) in[3 + j] = g[j];

        float l0 = linb[0], l1 = linb[1];
        #pragma unroll
        for (int j = 0; j < 3 + AFN; j++) {
            l0 += in[j] * linw[j];
            l1 += in[j] * linw[(3 + AFN) + j];
        }
        float m = fmaxf(l0, l1);
        float lse = m + logf(expf(l0 - m) + expf(l1 - m));
        float lp0 = l0 - lse, lp1 = l1 - lse;
        float mm = fmaxf(lp0, lp1);
        float ee0 = expf(lp0 - mm), ee1 = expf(lp1 - mm);
        out[1 + n] = ee1 / (ee0 + ee1);
        int lab = labels[n];
        float lp = (lab == 0) ? lp0 : lp1;
        costp[wid] = -lp * (1.0f / NS);
    }
    __syncthreads();
    if (tid == 0) {
        atomicAdd(&out[0], costp[0] + costp[1] + costp[2] + costp[3]);
    }
}

// ---------------------------------------------------------------------------
extern "C" void kernel_launch(void* const* d_in, const int* in_sizes, int n_in,
                              void* d_out, int out_size, void* d_ws, size_t ws_size,
                              hipStream_t stream)
{
    (void)in_sizes; (void)n_in; (void)out_size; (void)ws_size;
    const float* se  = (const float*)d_in[0];
    const float* qe  = (const float*)d_in[1];
    const float* gaf = (const float*)d_in[2];
    const int*   lab = (const int*)d_in[3];
    const float* w1  = (const float*)d_in[4];
    const float* b1  = (const float*)d_in[5];
    const float* w2  = (const float*)d_in[6];
    const float* b2  = (const float*)d_in[7];
    const float* lw  = (const float*)d_in[8];
    const float* lb  = (const float*)d_in[9];
    float* out = (float*)d_out;
    float* ws  = (float*)d_ws;   // needs WS_TOTAL*4 = 520704 bytes

    hipLaunchKernelGGL(prep_kernel, dim3(1), dim3(256), 0, stream,
                       qe, w1, b1, w2, b2, ws, out);
    hipLaunchKernelGGL(stream_kernel, dim3(NS), dim3(256), 0, stream,
                       se, ws);
    hipLaunchKernelGGL(post_kernel, dim3(NS / 4), dim3(256), 0, stream,
                       se, gaf, lab, b1, b2, lw, lb, ws, out);
}

// Round 3
// 472.315 us; speedup vs baseline: 1.0445x; 1.0366x over previous
//
#include <hip/hip_runtime.h>
#include <math.h>

// Problem constants (reference: N, L, LQ, D, AF, K = 4096, 512, 32, 30, 10, 4)
#define NS 4096
#define LL 512
#define LQS 32
#define DD 30
#define AFN 10
#define KW 4

// Workspace layout (floats). All 30x30 tables stored TRANSPOSED: tbl[ii*30+o]
// so post_kernel's per-lane (lane=o) reads at inner index ii are coalesced.
enum {
  QRAW = 0,     // [30] mean of question_embeds over LQ
  Q1G  = 30,    // [30] gpool of conv1(q)
  Q2G  = 60,    // [30] gpool of conv2(windowpool(conv1(q)))
  NRM  = 90,    // [3]  norms of the three q vectors
  WS1  = 96,    // [900] sum_k conv1_w[o][i][k]          (transposed)
  WS2  = 996,   // [900] sum_k conv2_w[o][i][k]          (transposed)
  OA0  = 1896,  // [900] 3*w3 + 2*w2 + w1  (row 0)       (transposed)
  OA1  = 2796,  // [900] 2*w3 + w2         (row 1)       (transposed)
  OA2  = 3696,  // [900] w3                (row 2)       (transposed)
  OB0  = 4596,  // [900] w0                (row L-3)     (transposed)
  OB1  = 5496,  // [900] w1 + 2*w0         (row L-2)     (transposed)
  OB2  = 6396,  // [900] w2 + 2*w1 + 3*w0  (row L-1)     (transposed)
  SARR = 7296,  // [NS*DD] per-sentence channel sums
  WS_TOTAL = SARR + NS * DD
};

// ---------------------------------------------------------------------------
// Kernel 1 (fused): block 0 = question-side pipeline + weight transforms +
// zero cost accumulator; blocks 1..NS = pure streaming channel sums.
// ---------------------------------------------------------------------------
__global__ __launch_bounds__(256) void prep_stream_kernel(
    const float* __restrict__ se,   // [N, L, D]
    const float* __restrict__ qe,   // [LQ, D]
    const float* __restrict__ w1,   // [D, D, K]
    const float* __restrict__ b1,   // [D]
    const float* __restrict__ w2,   // [D, D, K]
    const float* __restrict__ b2,   // [D]
    float* __restrict__ ws,
    float* __restrict__ out)
{
    const int tid = threadIdx.x;

    if (blockIdx.x != 0) {
        // ----- streaming block: sentence n -----
        const int n = blockIdx.x - 1;
        const float* base = se + (size_t)n * (LL * DD);
        __shared__ float partial[960];

        if (tid < 240) {
            const float4* p = (const float4*)base + tid;
            float sx = 0.f, sy = 0.f, sz = 0.f, sw = 0.f;
            #pragma unroll
            for (int it = 0; it < 16; it++) {
                float4 v = p[it * 240];
                sx += v.x; sy += v.y; sz += v.z; sw += v.w;
            }
            partial[4 * tid + 0] = sx;
            partial[4 * tid + 1] = sy;
            partial[4 * tid + 2] = sz;
            partial[4 * tid + 3] = sw;
        }
        __syncthreads();
        // flat index f aggregates channel f % 30 (960 % 30 == 0)
        if (tid < DD) {
            float a = 0.f;
            #pragma unroll
            for (int m = 0; m < 32; m++) a += partial[tid + DD * m];
            ws[SARR + n * DD + tid] = a;
        }
        return;
    }

    // ----- prep block -----
    __shared__ float qT[DD][LQS];      // q[channel][t]
    __shared__ float q1c[DD][LQS + 3];
    __shared__ float q1w[DD][LQS];
    __shared__ float q2c[DD][LQS + 3];
    __shared__ float qpool[3][DD];

    for (int f = tid; f < LQS * DD; f += 256) {
        qT[f % DD][f / DD] = qe[f];
    }
    __syncthreads();

    // conv1
    for (int idx = tid; idx < DD * (LQS + 3); idx += 256) {
        int o = idx / (LQS + 3), t = idx % (LQS + 3);
        float acc = b1[o];
        for (int i = 0; i < DD; i++) {
            const float* w = w1 + (o * DD + i) * KW;
            #pragma unroll
            for (int k = 0; k < KW; k++) {
                int j = t + k - 3;
                if (j >= 0 && j < LQS) acc += qT[i][j] * w[k];
            }
        }
        q1c[o][t] = acc;
    }
    __syncthreads();

    // window pool
    for (int idx = tid; idx < DD * LQS; idx += 256) {
        int o = idx / LQS, t = idx % LQS;
        q1w[o][t] = 0.25f * (q1c[o][t] + q1c[o][t + 1] + q1c[o][t + 2] + q1c[o][t + 3]);
    }
    __syncthreads();

    // conv2
    for (int idx = tid; idx < DD * (LQS + 3); idx += 256) {
        int o = idx / (LQS + 3), t = idx % (LQS + 3);
        float acc = b2[o];
        for (int i = 0; i < DD; i++) {
            const float* w = w2 + (o * DD + i) * KW;
            #pragma unroll
            for (int k = 0; k < KW; k++) {
                int j = t + k - 3;
                if (j >= 0 && j < LQS) acc += q1w[i][j] * w[k];
            }
        }
        q2c[o][t] = acc;
    }
    __syncthreads();

    if (tid < DD) {
        float a = 0.f;
        for (int t = 0; t < LQS; t++) a += qT[tid][t];
        qpool[0][tid] = a * (1.0f / LQS);
        float g1 = 0.f;
        for (int t = 0; t < LQS + 3; t++) g1 += q1c[tid][t];
        qpool[1][tid] = g1 * (1.0f / (LQS + 3));
        float g2 = 0.f;
        for (int t = 0; t < LQS + 3; t++) g2 += q2c[tid][t];
        qpool[2][tid] = g2 * (1.0f / (LQS + 3));
        ws[QRAW + tid] = qpool[0][tid];
        ws[Q1G + tid]  = qpool[1][tid];
        ws[Q2G + tid]  = qpool[2][tid];
    }
    __syncthreads();
    if (tid < 3) {
        float s = 0.f;
        for (int i = 0; i < DD; i++) { float v = qpool[tid][i]; s += v * v; }
        ws[NRM + tid] = sqrtf(s);
    }
    if (tid == 0) out[0] = 0.0f;  // cost accumulator

    // weight transforms (stored transposed: [inner ii][out o])
    for (int idx = tid; idx < DD * DD; idx += 256) {
        int o = idx / DD, i = idx % DD;
        int tr = i * DD + o;
        const float* w = w1 + idx * KW;
        float a = w[0], b = w[1], c = w[2], d = w[3];
        ws[WS1 + tr] = a + b + c + d;
        ws[OA0 + tr] = 3.f * d + 2.f * c + b;
        ws[OA1 + tr] = 2.f * d + c;
        ws[OA2 + tr] = d;
        ws[OB0 + tr] = a;
        ws[OB1 + tr] = b + 2.f * a;
        ws[OB2 + tr] = c + 2.f * b + 3.f * a;
        const float* v = w2 + idx * KW;
        ws[WS2 + tr] = v[0] + v[1] + v[2] + v[3];
    }
}

// ---------------------------------------------------------------------------
// Kernel 2: one sentence per WAVE (lanes 0..29 active), all cross-channel
// math via __shfl broadcasts; transposed tables -> coalesced VMEM.
// ---------------------------------------------------------------------------
__global__ __launch_bounds__(256) void post_kernel(
    const float* __restrict__ se,    // [N, L, D]
    const float* __restrict__ gaf,   // [N, AF]
    const int*   __restrict__ labels,// [N]
    const float* __restrict__ b1,    // [D]
    const float* __restrict__ b2,    // [D]
    const float* __restrict__ linw,  // [2, 13]
    const float* __restrict__ linb,  // [2]
    const float* __restrict__ ws,
    float* __restrict__ out)         // [1 + N]
{
    const int tid  = threadIdx.x;
    const int wid  = tid >> 6;
    const int lane = tid & 63;
    const int n    = blockIdx.x * 4 + wid;

    __shared__ float costp[4];

    const bool act = (lane < DD);
    const int  ic  = act ? lane : 0;

    // per-lane channel data
    float S_i, e0r, e1r, e2r, e3r, e4r, e5r, bb1, bb2;
    {
        const float* base = se + (size_t)n * (LL * DD);
        S_i = ws[SARR + n * DD + ic];
        e0r = base[0 * DD + ic];
        e1r = base[1 * DD + ic];
        e2r = base[2 * DD + ic];
        e3r = base[509 * DD + ic];
        e4r = base[510 * DD + ic];
        e5r = base[511 * DD + ic];
        bb1 = b1[ic];
        bb2 = b2[ic];
    }

    // dotS[o] = sum_ii S[ii]*WS1[o][ii]; tables transposed: tbl[ii*DD + o]
    float dotS = 0.f, edge = 0.f;
    #pragma unroll 6
    for (int ii = 0; ii < DD; ii++) {
        float s   = __shfl(S_i, ii, 64);
        float b0  = __shfl(e0r, ii, 64);
        float b1v = __shfl(e1r, ii, 64);
        float b2v = __shfl(e2r, ii, 64);
        float b3v = __shfl(e3r, ii, 64);
        float b4v = __shfl(e4r, ii, 64);
        float b5v = __shfl(e5r, ii, 64);
        const int t = ii * DD + ic;
        dotS += s * ws[WS1 + t];
        edge += b0 * ws[OA0 + t] + b1v * ws[OA1 + t] + b2v * ws[OA2 + t]
              + b3v * ws[OB0 + t] + b4v * ws[OB1 + t] + b5v * ws[OB2 + t];
    }
    float s1g = dotS * (1.0f / (LL + 3)) + bb1;
    float Tv  = dotS + (float)LL * bb1 - 0.25f * edge;

    float dot2 = 0.f;
    #pragma unroll 6
    for (int ii = 0; ii < DD; ii++) {
        float tv = __shfl(Tv, ii, 64);
        dot2 += tv * ws[WS2 + ii * DD + ic];
    }
    float s2g = dot2 * (1.0f / (LL + 3)) + bb2;

    // six dot products of length 30
    float qv = (n == 0) ? ws[QRAW + ic] : ws[Q2G + ic];
    float q1 = ws[Q1G + ic];
    float q2 = ws[Q2G + ic];
    float p0 = act ? qv * S_i : 0.f;
    float p1 = act ? S_i * S_i : 0.f;
    float p2 = act ? q1 * s1g : 0.f;
    float p3 = act ? s1g * s1g : 0.f;
    float p4 = act ? q2 * s2g : 0.f;
    float p5 = act ? s2g * s2g : 0.f;
    #pragma unroll
    for (int off = 32; off >= 1; off >>= 1) {
        p0 += __shfl_xor(p0, off, 64);
        p1 += __shfl_xor(p1, off, 64);
        p2 += __shfl_xor(p2, off, 64);
        p3 += __shfl_xor(p3, off, 64);
        p4 += __shfl_xor(p4, off, 64);
        p5 += __shfl_xor(p5, off, 64);
    }

    if (lane == 0) {
        float nq = (n == 0) ? ws[NRM + 0] : ws[NRM + 2];
        float sim1 = p0 / (nq * sqrtf(p1));
        float sim2 = p2 / (ws[NRM + 1] * sqrtf(p3));
        float sim3 = p4 / (ws[NRM + 2] * sqrtf(p5));

        float in[3 + AFN];
        in[0] = sim1; in[1] = sim2; in[2] = sim3;
        const float* g = gaf + (size_t)n * AFN;
        #pragma unroll
        for (int j = 0; j < AFN; j++) in[3 + j] = g[j];

        float l0 = linb[0], l1 = linb[1];
        #pragma unroll
        for (int j = 0; j < 3 + AFN; j++) {
            l0 += in[j] * linw[j];
            l1 += in[j] * linw[(3 + AFN) + j];
        }
        float m = fmaxf(l0, l1);
        float lse = m + logf(expf(l0 - m) + expf(l1 - m));
        float lp0 = l0 - lse, lp1 = l1 - lse;
        float mm = fmaxf(lp0, lp1);
        float ee0 = expf(lp0 - mm), ee1 = expf(lp1 - mm);
        out[1 + n] = ee1 / (ee0 + ee1);
        int lab = labels[n];
        float lp = (lab == 0) ? lp0 : lp1;
        costp[wid] = -lp * (1.0f / NS);
    }
    __syncthreads();
    if (tid == 0) {
        atomicAdd(&out[0], costp[0] + costp[1] + costp[2] + costp[3]);
    }
}

// ---------------------------------------------------------------------------
extern "C" void kernel_launch(void* const* d_in, const int* in_sizes, int n_in,
                              void* d_out, int out_size, void* d_ws, size_t ws_size,
                              hipStream_t stream)
{
    (void)in_sizes; (void)n_in; (void)out_size; (void)ws_size;
    const float* se  = (const float*)d_in[0];
    const float* qe  = (const float*)d_in[1];
    const float* gaf = (const float*)d_in[2];
    const int*   lab = (const int*)d_in[3];
    const float* w1  = (const float*)d_in[4];
    const float* b1  = (const float*)d_in[5];
    const float* w2  = (const float*)d_in[6];
    const float* b2  = (const float*)d_in[7];
    const float* lw  = (const float*)d_in[8];
    const float* lb  = (const float*)d_in[9];
    float* out = (float*)d_out;
    float* ws  = (float*)d_ws;   // needs WS_TOTAL*4 = 520704 bytes

    hipLaunchKernelGGL(prep_stream_kernel, dim3(NS + 1), dim3(256), 0, stream,
                       se, qe, w1, b1, w2, b2, ws, out);
    hipLaunchKernelGGL(post_kernel, dim3(NS / 4), dim3(256), 0, stream,
                       se, gaf, lab, b1, b2, lw, lb, ws, out);
}

// Round 4
// 424.375 us; speedup vs baseline: 1.1625x; 1.1130x over previous
//
#include <hip/hip_runtime.h>
#include <math.h>

// Problem constants (reference: N, L, LQ, D, AF, K = 4096, 512, 32, 30, 10, 4)
#define NS 4096
#define LL 512
#define LQS 32
#define DD 30
#define AFN 10
#define KW 4

// Workspace layout (floats). All 30x30 tables stored TRANSPOSED: tbl[ii*30+o]
// so the tail's per-lane (lane=o) reads at inner index ii are conflict-free.
enum {
  QRAW = 0,     // [30] mean of question_embeds over LQ
  Q1G  = 30,    // [30] gpool of conv1(q)
  Q2G  = 60,    // [30] gpool of conv2(windowpool(conv1(q)))
  NRM  = 90,    // [3] norms (+3 pad)
  WS1  = 96,    // [900] sum_k conv1_w   (transposed)
  WS2  = 996,   // [900] sum_k conv2_w   (transposed)
  OA0  = 1896,  // [900] 3*w3+2*w2+w1  (row 0)    (transposed)
  OA1  = 2796,  // [900] 2*w3+w2       (row 1)    (transposed)
  OA2  = 3696,  // [900] w3            (row 2)    (transposed)
  OB0  = 4596,  // [900] w0            (row L-3)  (transposed)
  OB1  = 5496,  // [900] w1+2*w0       (row L-2)  (transposed)
  OB2  = 6396,  // [900] w2+2*w1+3*w0  (row L-1)  (transposed)
  WTOT = 7296   // staged wholesale into LDS by every streaming block
};

// ---------------------------------------------------------------------------
// Kernel 1: question pipeline + weight transforms. ONE block. Weights staged
// in LDS first (the round-3 202us kernel was latency-bound on ~480 dependent
// GLOBAL weight reads per thread inside the conv loops).
// ---------------------------------------------------------------------------
__global__ __launch_bounds__(256) void prep_kernel(
    const float* __restrict__ qe,   // [LQ, D]
    const float* __restrict__ w1,   // [D, D, K]
    const float* __restrict__ b1,   // [D]
    const float* __restrict__ w2,   // [D, D, K]
    const float* __restrict__ b2,   // [D]
    float* __restrict__ ws,
    float* __restrict__ out)
{
    __shared__ float w1s[DD * DD * KW];   // 3600
    __shared__ float w2s[DD * DD * KW];   // 3600
    __shared__ float qT[DD][LQS];
    __shared__ float q1c[DD][LQS + 3];
    __shared__ float q1w[DD][LQS];
    __shared__ float q2c[DD][LQS + 3];
    __shared__ float qpool[3][DD];
    const int tid = threadIdx.x;

    // coalesced LDS staging of both weight tensors (independent loads)
    for (int f = tid; f < DD * DD * KW; f += 256) {
        w1s[f] = w1[f];
        w2s[f] = w2[f];
    }
    for (int f = tid; f < LQS * DD; f += 256) {
        qT[f % DD][f / DD] = qe[f];
    }
    __syncthreads();

    // conv1 (all operands now in LDS)
    for (int idx = tid; idx < DD * (LQS + 3); idx += 256) {
        int o = idx / (LQS + 3), t = idx % (LQS + 3);
        float acc = b1[o];
        for (int i = 0; i < DD; i++) {
            const float* w = w1s + (o * DD + i) * KW;
            #pragma unroll
            for (int k = 0; k < KW; k++) {
                int j = t + k - 3;
                if (j >= 0 && j < LQS) acc += qT[i][j] * w[k];
            }
        }
        q1c[o][t] = acc;
    }
    __syncthreads();

    // window pool
    for (int idx = tid; idx < DD * LQS; idx += 256) {
        int o = idx / LQS, t = idx % LQS;
        q1w[o][t] = 0.25f * (q1c[o][t] + q1c[o][t + 1] + q1c[o][t + 2] + q1c[o][t + 3]);
    }
    __syncthreads();

    // conv2
    for (int idx = tid; idx < DD * (LQS + 3); idx += 256) {
        int o = idx / (LQS + 3), t = idx % (LQS + 3);
        float acc = b2[o];
        for (int i = 0; i < DD; i++) {
            const float* w = w2s + (o * DD + i) * KW;
            #pragma unroll
            for (int k = 0; k < KW; k++) {
                int j = t + k - 3;
                if (j >= 0 && j < LQS) acc += q1w[i][j] * w[k];
            }
        }
        q2c[o][t] = acc;
    }
    __syncthreads();

    if (tid < DD) {
        float a = 0.f;
        for (int t = 0; t < LQS; t++) a += qT[tid][t];
        qpool[0][tid] = a * (1.0f / LQS);
        float g1 = 0.f;
        for (int t = 0; t < LQS + 3; t++) g1 += q1c[tid][t];
        qpool[1][tid] = g1 * (1.0f / (LQS + 3));
        float g2 = 0.f;
        for (int t = 0; t < LQS + 3; t++) g2 += q2c[tid][t];
        qpool[2][tid] = g2 * (1.0f / (LQS + 3));
        ws[QRAW + tid] = qpool[0][tid];
        ws[Q1G + tid]  = qpool[1][tid];
        ws[Q2G + tid]  = qpool[2][tid];
    }
    __syncthreads();
    if (tid < 3) {
        float s = 0.f;
        for (int i = 0; i < DD; i++) { float v = qpool[tid][i]; s += v * v; }
        ws[NRM + tid] = sqrtf(s);
    }
    if (tid >= 3 && tid < 6) ws[NRM + tid] = 0.f;  // pad so ws[0..7296) is fully defined
    if (tid == 0) out[0] = 0.0f;                   // cost accumulator

    // weight transforms from LDS (stored transposed: [inner i][out o])
    for (int idx = tid; idx < DD * DD; idx += 256) {
        int o = idx / DD, i = idx % DD;
        int tr = i * DD + o;
        const float* w = w1s + idx * KW;
        float a = w[0], b = w[1], c = w[2], d = w[3];
        ws[WS1 + tr] = a + b + c + d;
        ws[OA0 + tr] = 3.f * d + 2.f * c + b;
        ws[OA1 + tr] = 2.f * d + c;
        ws[OA2 + tr] = d;
        ws[OB0 + tr] = a;
        ws[OB1 + tr] = b + 2.f * a;
        ws[OB2 + tr] = c + 2.f * b + 3.f * a;
        const float* v = w2s + idx * KW;
        ws[WS2 + tr] = v[0] + v[1] + v[2] + v[3];
    }
}

// ---------------------------------------------------------------------------
// Kernel 2: one block per sentence. Stream 61440 B (240 threads x 16 float4),
// stage the 29 KB table block into LDS (L2-hot broadcast), then wave 0
// finishes the whole sentence: analytic conv-pool algebra -> sims -> MLP ->
// log-softmax -> emit + per-block cost atomic. No SARR, no third kernel.
// ---------------------------------------------------------------------------
__global__ __launch_bounds__(256) void stream_post_kernel(
    const float* __restrict__ se,    // [N, L, D]
    const float* __restrict__ gaf,   // [N, AF]
    const int*   __restrict__ labels,// [N]
    const float* __restrict__ b1,    // [D]
    const float* __restrict__ b2,    // [D]
    const float* __restrict__ linw,  // [2, 13]
    const float* __restrict__ linb,  // [2]
    const float* __restrict__ ws,
    float* __restrict__ out)         // [1 + N]
{
    const int n   = blockIdx.x;
    const int tid = threadIdx.x;
    const float* base = se + (size_t)n * (LL * DD);

    __shared__ float tabs[WTOT];     // ws[0..7296): q vectors + 8 tables
    __shared__ float partial[960];
    __shared__ float bnd[6][DD];

    // stage tables, coalesced float4 (1824 vec4 / 256 threads ~ 8 each)
    {
        const float4* src = (const float4*)ws;
        float4* dst = (float4*)tabs;
        #pragma unroll
        for (int f = tid; f < WTOT / 4; f += 256) dst[f] = src[f];
    }
    // stream the sentence
    if (tid < 240) {
        const float4* p = (const float4*)base + tid;
        float sx = 0.f, sy = 0.f, sz = 0.f, sw = 0.f;
        #pragma unroll
        for (int it = 0; it < 16; it++) {
            float4 v = p[it * 240];
            sx += v.x; sy += v.y; sz += v.z; sw += v.w;
        }
        partial[4 * tid + 0] = sx;
        partial[4 * tid + 1] = sy;
        partial[4 * tid + 2] = sz;
        partial[4 * tid + 3] = sw;
    }
    // boundary rows 0,1,2,509,510,511 (L1-hot: just streamed)
    if (tid < 180) {
        int r = tid / DD, c = tid % DD;
        int j = (r < 3) ? r : (LL - 6 + r);
        bnd[r][c] = base[j * DD + c];
    }
    __syncthreads();

    // ---- tail: wave 0 only ----
    if (tid < 64) {
        const int lane = tid;
        const bool act = (lane < DD);
        const int  ic  = act ? lane : 0;

        // channel sum (flat index f aggregates channel f % 30)
        float S_i = 0.f;
        #pragma unroll
        for (int m = 0; m < 32; m++) S_i += partial[ic + DD * m];

        float e0r = bnd[0][ic], e1r = bnd[1][ic], e2r = bnd[2][ic];
        float e3r = bnd[3][ic], e4r = bnd[4][ic], e5r = bnd[5][ic];
        float bb1 = b1[ic], bb2 = b2[ic];

        // dotS[o] = sum_ii S[ii]*WS1[ii][o]; edge analogous (tables transposed)
        float dotS = 0.f, edge = 0.f;
        #pragma unroll 6
        for (int ii = 0; ii < DD; ii++) {
            float s   = __shfl(S_i, ii, 64);
            float b0  = __shfl(e0r, ii, 64);
            float b1v = __shfl(e1r, ii, 64);
            float b2v = __shfl(e2r, ii, 64);
            float b3v = __shfl(e3r, ii, 64);
            float b4v = __shfl(e4r, ii, 64);
            float b5v = __shfl(e5r, ii, 64);
            const int t = ii * DD + ic;
            dotS += s * tabs[WS1 + t];
            edge += b0 * tabs[OA0 + t] + b1v * tabs[OA1 + t] + b2v * tabs[OA2 + t]
                  + b3v * tabs[OB0 + t] + b4v * tabs[OB1 + t] + b5v * tabs[OB2 + t];
        }
        float s1g = dotS * (1.0f / (LL + 3)) + bb1;
        float Tv  = dotS + (float)LL * bb1 - 0.25f * edge;

        float dot2 = 0.f;
        #pragma unroll 6
        for (int ii = 0; ii < DD; ii++) {
            float tv = __shfl(Tv, ii, 64);
            dot2 += tv * tabs[WS2 + ii * DD + ic];
        }
        float s2g = dot2 * (1.0f / (LL + 3)) + bb2;

        // six length-30 dot products (cos is scale-invariant in s_raw -> use S)
        float qv = (n == 0) ? tabs[QRAW + ic] : tabs[Q2G + ic];
        float q1 = tabs[Q1G + ic];
        float q2 = tabs[Q2G + ic];
        float p0 = act ? qv * S_i : 0.f;
        float p1 = act ? S_i * S_i : 0.f;
        float p2 = act ? q1 * s1g : 0.f;
        float p3 = act ? s1g * s1g : 0.f;
        float p4 = act ? q2 * s2g : 0.f;
        float p5 = act ? s2g * s2g : 0.f;
        #pragma unroll
        for (int off = 32; off >= 1; off >>= 1) {
            p0 += __shfl_xor(p0, off, 64);
            p1 += __shfl_xor(p1, off, 64);
            p2 += __shfl_xor(p2, off, 64);
            p3 += __shfl_xor(p3, off, 64);
            p4 += __shfl_xor(p4, off, 64);
            p5 += __shfl_xor(p5, off, 64);
        }

        if (lane == 0) {
            float nq = (n == 0) ? tabs[NRM + 0] : tabs[NRM + 2];
            float sim1 = p0 / (nq * sqrtf(p1));
            float sim2 = p2 / (tabs[NRM + 1] * sqrtf(p3));
            float sim3 = p4 / (tabs[NRM + 2] * sqrtf(p5));

            float in[3 + AFN];
            in[0] = sim1; in[1] = sim2; in[2] = sim3;
            const float* g = gaf + (size_t)n * AFN;
            #pragma unroll
            for (int j = 0; j < AFN; j++) in[3 + j] = g[j];

            float l0 = linb[0], l1 = linb[1];
            #pragma unroll
            for (int j = 0; j < 3 + AFN; j++) {
                l0 += in[j] * linw[j];
                l1 += in[j] * linw[(3 + AFN) + j];
            }
            float m = fmaxf(l0, l1);
            float lse = m + logf(expf(l0 - m) + expf(l1 - m));
            float lp0 = l0 - lse, lp1 = l1 - lse;
            float mm = fmaxf(lp0, lp1);
            float ee0 = expf(lp0 - mm), ee1 = expf(lp1 - mm);
            out[1 + n] = ee1 / (ee0 + ee1);
            int lab = labels[n];
            float lp = (lab == 0) ? lp0 : lp1;
            atomicAdd(&out[0], -lp * (1.0f / NS));
        }
    }
}

// ---------------------------------------------------------------------------
extern "C" void kernel_launch(void* const* d_in, const int* in_sizes, int n_in,
                              void* d_out, int out_size, void* d_ws, size_t ws_size,
                              hipStream_t stream)
{
    (void)in_sizes; (void)n_in; (void)out_size; (void)ws_size;
    const float* se  = (const float*)d_in[0];
    const float* qe  = (const float*)d_in[1];
    const float* gaf = (const float*)d_in[2];
    const int*   lab = (const int*)d_in[3];
    const float* w1  = (const float*)d_in[4];
    const float* b1  = (const float*)d_in[5];
    const float* w2  = (const float*)d_in[6];
    const float* b2  = (const float*)d_in[7];
    const float* lw  = (const float*)d_in[8];
    const float* lb  = (const float*)d_in[9];
    float* out = (float*)d_out;
    float* ws  = (float*)d_ws;   // needs WTOT*4 = 29184 bytes

    hipLaunchKernelGGL(prep_kernel, dim3(1), dim3(256), 0, stream,
                       qe, w1, b1, w2, b2, ws, out);
    hipLaunchKernelGGL(stream_post_kernel, dim3(NS), dim3(256), 0, stream,
                       se, gaf, lab, b1, b2, lw, lb, ws, out);
}